// Round 1
// baseline (967.440 us; speedup 1.0000x reference)
//
#include <hip/hip_runtime.h>
#include <hip/hip_bf16.h>

#define B_ 2
#define N_ 4096
#define D_ 1024
#define H_ 16
#define NY 4095          // pooled tree rows per batch
#define TOT 8191         // N_ + NY

typedef __attribute__((ext_vector_type(8))) short bf16x8;
typedef __attribute__((ext_vector_type(4))) short s16x4;
typedef __attribute__((ext_vector_type(4))) float f32x4;

__device__ inline float b2f(short s) {
  unsigned u = ((unsigned)(unsigned short)s) << 16;
  float f; __builtin_memcpy(&f, &u, 4); return f;
}
__device__ inline short f2bf(float f) {
  unsigned u; __builtin_memcpy(&u, &f, 4);
  unsigned r = (u + 0x7fffu + ((u >> 16) & 1u)) >> 16;
  return (short)r;
}

__device__ inline void gl_lds16(const short* g, short* l) {
  __builtin_amdgcn_global_load_lds(
      (const __attribute__((address_space(1))) void*)g,
      (__attribute__((address_space(3))) void*)l, 16, 0, 0);
}

// ---------------- conversions / pooling ----------------

__global__ __launch_bounds__(256) void cvt_bf16(const float* __restrict__ s,
                                                short* __restrict__ d) {
  long t = (((long)blockIdx.x << 8) + threadIdx.x) << 2;
  float4 v = *(const float4*)(s + t);
  s16x4 o; o.x = f2bf(v.x); o.y = f2bf(v.y); o.z = f2bf(v.z); o.w = f2bf(v.w);
  *(s16x4*)(d + t) = o;
}

// level-1 pooling straight from fp32 x
__global__ __launch_bounds__(256) void pool_first(const float* __restrict__ x,
                                                  short* __restrict__ yin) {
  long t = ((long)blockIdx.x << 8) + threadIdx.x;
  int d = (int)(t & 1023);
  int j = (int)((t >> 10) & 2047);
  int b = (int)(t >> 21);
  const float* xb = x + (((long)(b * N_ + (j << 1))) << 10) + d;
  yin[(((long)(b * NY + j)) << 10) + d] = f2bf(0.5f * (xb[0] + xb[1024]));
}

// level l from level l-1 inside yin
__global__ __launch_bounds__(256) void pool_next(short* __restrict__ yin,
                                                 int offp, int off, int lg) {
  long t = ((long)blockIdx.x << 8) + threadIdx.x;
  int d = (int)(t & 1023);
  int j = (int)((t >> 10) & ((1 << lg) - 1));
  int b = (int)(t >> (10 + lg));
  long sb = (((long)(b * NY + offp + (j << 1))) << 10) + d;
  float v = 0.5f * (b2f(yin[sb]) + b2f(yin[sb + 1024]));
  yin[(((long)(b * NY + off + j)) << 10) + d] = f2bf(v);
}

// ---------------- GEMM: C[b,r,c] = sum_k A[b,r,k] * W[c,k] (+bias) ----------------
// A bf16 (rows x 1024), W bf16 (1024 x 1024) row-major (out,in). 128x128 tile,
// BK=32, 4 waves, m97-style global_load_lds staging, mfma 16x16x32 bf16.

template <int STORE_F32, int HAS_BIAS>
__global__ __launch_bounds__(256) void gemm_bt(const short* __restrict__ A,
                                               const short* __restrict__ W,
                                               void* __restrict__ Cv,
                                               const float* __restrict__ bias,
                                               int Mb, long sA, long sC) {
  __shared__ short lA[128 * 32];
  __shared__ short lB[128 * 32];
  const int tid = threadIdx.x;
  const int wave = tid >> 6, lane = tid & 63;
  const int row0 = blockIdx.x * 128, col0 = blockIdx.y * 128;
  const short* Ab = A + (long)blockIdx.z * sA;

  f32x4 acc[4][4];
#pragma unroll
  for (int m = 0; m < 4; ++m)
#pragma unroll
    for (int n = 0; n < 4; ++n) acc[m][n] = (f32x4){0.f, 0.f, 0.f, 0.f};

  const int sr = lane >> 2;          // 0..15 row within 16-row stripe
  const int sk = (lane & 3) * 8;     // k element offset 0/8/16/24
  const int ra0 = wave * 32 + sr;
  const int ra1 = ra0 + 16;
  const int ga0 = (row0 + ra0 < Mb) ? (row0 + ra0) : (Mb - 1);
  const int ga1 = (row0 + ra1 < Mb) ? (row0 + ra1) : (Mb - 1);
  const short* aP0 = Ab + ((long)ga0 << 10) + sk;
  const short* aP1 = Ab + ((long)ga1 << 10) + sk;
  const short* wP0 = W + ((long)(col0 + ra0) << 10) + sk;
  const short* wP1 = W + ((long)(col0 + ra1) << 10) + sk;
  short* lA0 = lA + (wave * 2 + 0) * 512;
  short* lA1 = lA + (wave * 2 + 1) * 512;
  short* lB0 = lB + (wave * 2 + 0) * 512;
  short* lB1 = lB + (wave * 2 + 1) * 512;

  const int fr = lane & 15, fq = lane >> 4;
  const int wr = (wave >> 1) * 64, wc = (wave & 1) * 64;

  for (int kk = 0; kk < 1024; kk += 32) {
    __syncthreads();
    gl_lds16(aP0 + kk, lA0);
    gl_lds16(aP1 + kk, lA1);
    gl_lds16(wP0 + kk, lB0);
    gl_lds16(wP1 + kk, lB1);
    __syncthreads();
    bf16x8 af[4], bw[4];
#pragma unroll
    for (int m = 0; m < 4; ++m)
      af[m] = *(const bf16x8*)&lA[(wr + m * 16 + fr) * 32 + fq * 8];
#pragma unroll
    for (int n = 0; n < 4; ++n)
      bw[n] = *(const bf16x8*)&lB[(wc + n * 16 + fr) * 32 + fq * 8];
#pragma unroll
    for (int m = 0; m < 4; ++m)
#pragma unroll
      for (int n = 0; n < 4; ++n)
        acc[m][n] = __builtin_amdgcn_mfma_f32_16x16x32_bf16(af[m], bw[n],
                                                            acc[m][n], 0, 0, 0);
  }

#pragma unroll
  for (int n = 0; n < 4; ++n) {
    int col = col0 + wc + n * 16 + fr;
    float bv = HAS_BIAS ? bias[col] : 0.f;
#pragma unroll
    for (int m = 0; m < 4; ++m) {
#pragma unroll
      for (int q = 0; q < 4; ++q) {
        int row = row0 + wr + m * 16 + fq * 4 + q;
        if (row < Mb) {
          long off = (long)blockIdx.z * sC + ((long)row << 10) + col;
          float v = acc[m][n][q] + bv;
          if (STORE_F32) ((float*)Cv)[off] = v;
          else ((short*)Cv)[off] = f2bf(v);
        }
      }
    }
  }
}

// ---------------- per-level 3-key attention ----------------
// one wave per (b, parent p, head h); lane = dim.

__global__ __launch_bounds__(256) void attn_level(
    const short* __restrict__ Qp, const short* __restrict__ Kp,
    const short* __restrict__ Vp, const short* __restrict__ Kc,
    const short* __restrict__ Vc, short* __restrict__ ao, int pc, int off,
    int lg) {
  int wid = (blockIdx.x << 2) + (threadIdx.x >> 6);
  int lane = threadIdx.x & 63;
  int b = wid >> (lg + 4);
  int rem = wid & ((1 << (lg + 4)) - 1);
  int p = rem >> 4;
  int h = rem & 15;
  long base = (((long)(b * NY + off + p)) << 10) + h * 64 + lane;
  float q = b2f(Qp[base]);
  float kp = b2f(Kp[base]), vp = b2f(Vp[base]);
  long cb = (((long)(((b * pc) << 1) + (p << 1))) << 10) + h * 64 + lane;
  float k0 = b2f(Kc[cb]), v0 = b2f(Vc[cb]);
  float k1 = b2f(Kc[cb + 1024]), v1 = b2f(Vc[cb + 1024]);
  float d0 = q * kp, d1 = q * k0, d2 = q * k1;
#pragma unroll
  for (int s = 32; s >= 1; s >>= 1) {
    d0 += __shfl_xor(d0, s);
    d1 += __shfl_xor(d1, s);
    d2 += __shfl_xor(d2, s);
  }
  d0 *= 0.125f; d1 *= 0.125f; d2 *= 0.125f;
  float mx = fmaxf(d0, fmaxf(d1, d2));
  float e0 = __expf(d0 - mx), e1 = __expf(d1 - mx), e2 = __expf(d2 - mx);
  float inv = 1.0f / (e0 + e1 + e2);
  ao[base] = f2bf((e0 * vp + e1 * v0 + e2 * v1) * inv);
}

// ---------------- final 13-key sparse attention ----------------
// one wave per (b, i, h); lane = dim. FIDX/FMASK recomputed on the fly.

__global__ __launch_bounds__(256) void attn_final(const short* __restrict__ Q,
                                                  const short* __restrict__ Kf,
                                                  const short* __restrict__ Vf,
                                                  short* __restrict__ out) {
  int wid = (blockIdx.x << 2) + (threadIdx.x >> 6);
  int lane = threadIdx.x & 63;
  int b = wid >> 16;
  int i = (wid >> 4) & (N_ - 1);
  int h = wid & 15;
  long qoff = (((long)(b * N_ + i)) << 10) + h * 64 + lane;
  float q = b2f(Q[qoff]);
  long kvb = (((long)b * TOT) << 10) + h * 64 + lane;

  int idxs[13];
  unsigned mbits = 0;
  idxs[0] = i;
  int ncur = i;
#pragma unroll
  for (int lvl = 0; lvl < 12; ++lvl) {
    int pair, nx;
    if (lvl == 0) { pair = ncur; nx = ncur ^ 1; }
    else { pair = (ncur >> 1) + N_; nx = pair ^ 1; }
    bool valid = (nx <= 2 * N_ - 3);
    idxs[lvl + 1] = valid ? nx : (2 * N_ - 2);
    if (valid && (pair < nx)) mbits |= (1u << (lvl + 1));
    ncur = nx;
  }
  float dots[13], vv[13];
#pragma unroll
  for (int k = 0; k < 13; ++k) {
    long o = kvb + ((long)idxs[k] << 10);
    dots[k] = q * b2f(Kf[o]);
    vv[k] = b2f(Vf[o]);
  }
#pragma unroll
  for (int s = 32; s >= 1; s >>= 1) {
#pragma unroll
    for (int k = 0; k < 13; ++k) dots[k] += __shfl_xor(dots[k], s);
  }
  float mx = -1e30f;
#pragma unroll
  for (int k = 0; k < 13; ++k) {
    dots[k] = ((mbits >> k) & 1) ? -1e30f : dots[k] * 0.125f;
    mx = fmaxf(mx, dots[k]);
  }
  float se = 0.f, o = 0.f;
#pragma unroll
  for (int k = 0; k < 13; ++k) {
    float e = __expf(dots[k] - mx);
    se += e;
    o += e * vv[k];
  }
  out[qoff] = f2bf(o / se);
}

// ---------------- host orchestration ----------------

extern "C" void kernel_launch(void* const* d_in, const int* in_sizes, int n_in,
                              void* d_out, int out_size, void* d_ws,
                              size_t ws_size, hipStream_t stream) {
  const float* x = (const float*)d_in[0];
  const float* wsrc[8] = {(const float*)d_in[1], (const float*)d_in[2],
                          (const float*)d_in[3], (const float*)d_in[4],
                          (const float*)d_in[6], (const float*)d_in[7],
                          (const float*)d_in[8], (const float*)d_in[9]};
  const float* boy = (const float*)d_in[5];
  const float* box = (const float*)d_in[10];

  char* p = (char*)d_ws;
  auto alloc = [&](size_t n) {
    char* r = p;
    p += (n + 255) & ~(size_t)255;
    return r;
  };
  short* xbf = (short*)alloc((size_t)B_ * N_ * D_ * 2);
  short* yin = (short*)alloc((size_t)B_ * NY * D_ * 2);
  short* Qp = (short*)alloc((size_t)B_ * NY * D_ * 2);
  short* Kp = (short*)alloc((size_t)B_ * NY * D_ * 2);
  short* Vp = (short*)alloc((size_t)B_ * NY * D_ * 2);
  short* Kc = (short*)alloc((size_t)B_ * N_ * D_ * 2);
  short* Vc = (short*)alloc((size_t)B_ * N_ * D_ * 2);
  short* ao = (short*)alloc((size_t)B_ * NY * D_ * 2);
  short* ybf = (short*)alloc((size_t)B_ * NY * D_ * 2);
  short* Qx = (short*)alloc((size_t)B_ * N_ * D_ * 2);
  short* Kf = (short*)alloc((size_t)B_ * TOT * D_ * 2);
  short* Vf = (short*)alloc((size_t)B_ * TOT * D_ * 2);
  short* aout = (short*)alloc((size_t)B_ * N_ * D_ * 2);
  short* wb[8];
  for (int i = 0; i < 8; ++i) wb[i] = (short*)alloc((size_t)D_ * D_ * 2);

  // converts
  cvt_bf16<<<(B_ * N_ * D_) / 1024, 256, 0, stream>>>(x, xbf);
  for (int i = 0; i < 8; ++i)
    cvt_bf16<<<(D_ * D_) / 1024, 256, 0, stream>>>(wsrc[i], wb[i]);

  // pooling
  pool_first<<<(B_ * 2048 * D_) / 256, 256, 0, stream>>>(x, yin);
  int off[12], pc[12];
  pc[0] = 2048; off[0] = 0;
  for (int l = 1; l < 12; ++l) { pc[l] = pc[l - 1] >> 1; off[l] = off[l - 1] + pc[l - 1]; }
  for (int l = 1; l < 12; ++l)
    pool_next<<<(B_ * pc[l] * D_) / 256, 256, 0, stream>>>(yin, off[l - 1],
                                                           off[l], 11 - l);

  const long SY = (long)NY * D_;
  const long SX = (long)N_ * D_;
  const long ST = (long)TOT * D_;

  auto gemm = [&](const short* A, const short* W, void* C, const float* bias,
                  int Mb, long sA, long sC, int f32o, int hb) {
    dim3 g((Mb + 127) / 128, 8, B_);
    if (f32o)
      gemm_bt<1, 1><<<g, 256, 0, stream>>>(A, W, C, bias, Mb, sA, sC);
    else if (hb)
      gemm_bt<0, 1><<<g, 256, 0, stream>>>(A, W, C, bias, Mb, sA, sC);
    else
      gemm_bt<0, 0><<<g, 256, 0, stream>>>(A, W, C, (const float*)nullptr, Mb,
                                           sA, sC);
  };

  // tree-level Q/K/V of pooled rows + level-0 children K/V (of x)
  gemm(yin, wb[0], Qp, nullptr, NY, SY, SY, 0, 0);
  gemm(yin, wb[1], Kp, nullptr, NY, SY, SY, 0, 0);
  gemm(yin, wb[2], Vp, nullptr, NY, SY, SY, 0, 0);
  gemm(xbf, wb[1], Kc, nullptr, N_, SX, SX, 0, 0);
  gemm(xbf, wb[2], Vc, nullptr, N_, SX, SX, 0, 0);

  attn_level<<<8 * pc[0], 256, 0, stream>>>(Qp, Kp, Vp, Kc, Vc, ao, pc[0],
                                            off[0], 11);
  for (int l = 1; l < 12; ++l) {
    int cc = 2 * pc[l];  // children rows = rows of level l-1 output
    const short* prev = ao + (long)off[l - 1] * D_;
    gemm(prev, wb[1], Kc, nullptr, cc, SY, (long)cc * D_, 0, 0);
    gemm(prev, wb[2], Vc, nullptr, cc, SY, (long)cc * D_, 0, 0);
    attn_level<<<8 * pc[l], 256, 0, stream>>>(Qp, Kp, Vp, Kc, Vc, ao, pc[l],
                                              off[l], 11 - l);
  }

  // y projection (+bias), final Q/K/V, sparse attention, output projection
  gemm(ao, wb[3], ybf, boy, NY, SY, SY, 0, 1);
  gemm(xbf, wb[4], Qx, nullptr, N_, SX, SX, 0, 0);
  gemm(xbf, wb[5], Kf, nullptr, N_, SX, ST, 0, 0);
  gemm(ybf, wb[5], Kf + (long)N_ * D_, nullptr, NY, SY, ST, 0, 0);
  gemm(xbf, wb[6], Vf, nullptr, N_, SX, ST, 0, 0);
  gemm(ybf, wb[6], Vf + (long)N_ * D_, nullptr, NY, SY, ST, 0, 0);

  attn_final<<<(B_ * N_ * H_) / 4, 256, 0, stream>>>(Qx, Kf, Vf, aout);

  gemm(aout, wb[7], d_out, box, N_, SX, SX, 1, 1);
}

// Round 2
// 706.949 us; speedup vs baseline: 1.3685x; 1.3685x over previous
//
#include <hip/hip_runtime.h>
#include <hip/hip_bf16.h>

#define B_ 2
#define N_ 4096
#define NY 4095          // pooled tree rows per batch
#define TOT 8191

typedef __attribute__((ext_vector_type(8))) short bf16x8;
typedef __attribute__((ext_vector_type(4))) short s16x4;
typedef __attribute__((ext_vector_type(4))) float f32x4;

__device__ inline float b2f(short s) {
  unsigned u = ((unsigned)(unsigned short)s) << 16;
  float f; __builtin_memcpy(&f, &u, 4); return f;
}
__device__ inline short f2bf(float f) {
  unsigned u; __builtin_memcpy(&u, &f, 4);
  return (short)((u + 0x7fffu + ((u >> 16) & 1u)) >> 16);
}
__device__ inline float dot8(bf16x8 a, bf16x8 b) {
  float s = 0.f;
#pragma unroll
  for (int j = 0; j < 8; ++j) s += b2f(a[j]) * b2f(b[j]);
  return s;
}
__device__ inline void gl_lds16(const short* g, short* l) {
  __builtin_amdgcn_global_load_lds(
      (const __attribute__((address_space(1))) void*)g,
      (__attribute__((address_space(3))) void*)l, 16, 0, 0);
}

// ---------------- conversions ----------------

__global__ __launch_bounds__(256) void cvt_bf16(const float* __restrict__ s,
                                                short* __restrict__ d) {
  long t = (((long)blockIdx.x << 8) + threadIdx.x) << 2;
  float4 v = *(const float4*)(s + t);
  s16x4 o; o.x = f2bf(v.x); o.y = f2bf(v.y); o.z = f2bf(v.z); o.w = f2bf(v.w);
  *(s16x4*)(d + t) = o;
}

struct SrcPtrs { const float* p[8]; };

// 8 weight matrices (1M elems each) -> contiguous bf16 region
__global__ __launch_bounds__(256) void cvt_weights(SrcPtrs s,
                                                   short* __restrict__ dst) {
  long t = (((long)blockIdx.x << 8) + threadIdx.x) << 2;
  int which = (int)(t >> 20);
  const float* sp = s.p[which] + (t & 1048575);
  float4 v = *(const float4*)sp;
  s16x4 o; o.x = f2bf(v.x); o.y = f2bf(v.y); o.z = f2bf(v.z); o.w = f2bf(v.w);
  *(s16x4*)(dst + t) = o;
}

// ---------------- pooling (2 launches) ----------------
// pool_a: levels 0..3 directly from fp32 x (windows 2,4,8,16)
__global__ __launch_bounds__(256) void pool_a(const float* __restrict__ x,
                                              short* __restrict__ yin) {
  int wid = (blockIdx.x << 2) + (threadIdx.x >> 6);
  int lane = threadIdx.x & 63;
  int b = wid / 3840;
  int r = wid - b * 3840;
  int j, off, W;
  if (r < 2048)      { j = r;        off = 0;    W = 2; }
  else if (r < 3072) { j = r - 2048; off = 2048; W = 4; }
  else if (r < 3584) { j = r - 3072; off = 3072; W = 8; }
  else               { j = r - 3584; off = 3584; W = 16; }
  const float* xb = x + ((long)(b * N_ + j * W) << 10) + lane * 16;
  float acc[16];
#pragma unroll
  for (int c = 0; c < 16; ++c) acc[c] = 0.f;
  for (int w = 0; w < W; ++w) {
    const float4* rp = (const float4*)(xb + ((long)w << 10));
#pragma unroll
    for (int t = 0; t < 4; ++t) {
      float4 v = rp[t];
      acc[4 * t + 0] += v.x; acc[4 * t + 1] += v.y;
      acc[4 * t + 2] += v.z; acc[4 * t + 3] += v.w;
    }
  }
  float sc = 1.0f / (float)W;
  bf16x8 o0, o1;
#pragma unroll
  for (int jx = 0; jx < 8; ++jx) {
    o0[jx] = f2bf(acc[jx] * sc);
    o1[jx] = f2bf(acc[8 + jx] * sc);
  }
  short* dst = yin + ((long)(b * NY + off + j) << 10) + lane * 16;
  *(bf16x8*)dst = o0;
  *(bf16x8*)(dst + 8) = o1;
}

// pool_b: levels 4..11 from level-3 rows (256 rows/b at off 3584)
__global__ __launch_bounds__(256) void pool_b(short* __restrict__ yin) {
  int wid = (blockIdx.x << 2) + (threadIdx.x >> 6);
  if (wid >= B_ * 255) return;
  int lane = threadIdx.x & 63;
  int b = wid / 255;
  int r = wid - b * 255;
  int base = 0, size = 128, W = 2;
  while (r >= base + size) { base += size; size >>= 1; W <<= 1; }
  int j = r - base;
  const short* src = yin + ((long)(b * NY + 3584 + j * W) << 10) + lane * 16;
  float acc[16];
#pragma unroll
  for (int c = 0; c < 16; ++c) acc[c] = 0.f;
  for (int w = 0; w < W; ++w) {
    const short* rp = src + ((long)w << 10);
    bf16x8 v0 = *(const bf16x8*)rp;
    bf16x8 v1 = *(const bf16x8*)(rp + 8);
#pragma unroll
    for (int jx = 0; jx < 8; ++jx) {
      acc[jx] += b2f(v0[jx]);
      acc[8 + jx] += b2f(v1[jx]);
    }
  }
  float sc = 1.0f / (float)W;
  bf16x8 o0, o1;
#pragma unroll
  for (int jx = 0; jx < 8; ++jx) {
    o0[jx] = f2bf(acc[jx] * sc);
    o1[jx] = f2bf(acc[8 + jx] * sc);
  }
  short* dst = yin + ((long)(b * NY + 3840 + base + j) << 10) + lane * 16;
  *(bf16x8*)dst = o0;
  *(bf16x8*)(dst + 8) = o1;
}

// ---------------- GEMM: C[b,r,c] = sum_k A[b,r,k] * W[c,k] (+bias) --------
// A bf16 (rows x 1024), W bf16 (Ncols x 1024) row-major. 128x128 tile, BK=32.

template <int STORE_F32, int HAS_BIAS>
__global__ __launch_bounds__(256) void gemm_bt(const short* __restrict__ A,
                                               const short* __restrict__ W,
                                               void* __restrict__ Cv,
                                               const float* __restrict__ bias,
                                               int Mb, int Ncols, long sA,
                                               long sC) {
  __shared__ short lA[128 * 32];
  __shared__ short lB[128 * 32];
  const int tid = threadIdx.x;
  const int wave = tid >> 6, lane = tid & 63;
  const int row0 = blockIdx.x * 128, col0 = blockIdx.y * 128;
  const short* Ab = A + (long)blockIdx.z * sA;

  f32x4 acc[4][4];
#pragma unroll
  for (int m = 0; m < 4; ++m)
#pragma unroll
    for (int n = 0; n < 4; ++n) acc[m][n] = (f32x4){0.f, 0.f, 0.f, 0.f};

  const int sr = lane >> 2;
  const int sk = (lane & 3) * 8;
  const int ra0 = wave * 32 + sr;
  const int ra1 = ra0 + 16;
  const int ga0 = (row0 + ra0 < Mb) ? (row0 + ra0) : (Mb - 1);
  const int ga1 = (row0 + ra1 < Mb) ? (row0 + ra1) : (Mb - 1);
  const short* aP0 = Ab + ((long)ga0 << 10) + sk;
  const short* aP1 = Ab + ((long)ga1 << 10) + sk;
  const short* wP0 = W + ((long)(col0 + ra0) << 10) + sk;
  const short* wP1 = W + ((long)(col0 + ra1) << 10) + sk;
  short* lA0 = lA + (wave * 2 + 0) * 512;
  short* lA1 = lA + (wave * 2 + 1) * 512;
  short* lB0 = lB + (wave * 2 + 0) * 512;
  short* lB1 = lB + (wave * 2 + 1) * 512;

  const int fr = lane & 15, fq = lane >> 4;
  const int wr = (wave >> 1) * 64, wc = (wave & 1) * 64;

  for (int kk = 0; kk < 1024; kk += 32) {
    __syncthreads();
    gl_lds16(aP0 + kk, lA0);
    gl_lds16(aP1 + kk, lA1);
    gl_lds16(wP0 + kk, lB0);
    gl_lds16(wP1 + kk, lB1);
    __syncthreads();
    bf16x8 af[4], bw[4];
#pragma unroll
    for (int m = 0; m < 4; ++m)
      af[m] = *(const bf16x8*)&lA[(wr + m * 16 + fr) * 32 + fq * 8];
#pragma unroll
    for (int n = 0; n < 4; ++n)
      bw[n] = *(const bf16x8*)&lB[(wc + n * 16 + fr) * 32 + fq * 8];
#pragma unroll
    for (int m = 0; m < 4; ++m)
#pragma unroll
      for (int n = 0; n < 4; ++n)
        acc[m][n] = __builtin_amdgcn_mfma_f32_16x16x32_bf16(af[m], bw[n],
                                                            acc[m][n], 0, 0, 0);
  }

#pragma unroll
  for (int n = 0; n < 4; ++n) {
    int col = col0 + wc + n * 16 + fr;
    float bv = HAS_BIAS ? bias[col] : 0.f;
#pragma unroll
    for (int m = 0; m < 4; ++m) {
#pragma unroll
      for (int q = 0; q < 4; ++q) {
        int row = row0 + wr + m * 16 + fq * 4 + q;
        if (row < Mb) {
          long off = (long)blockIdx.z * sC + (long)row * Ncols + col;
          float v = acc[m][n][q] + bv;
          if (STORE_F32) ((float*)Cv)[off] = v;
          else ((short*)Cv)[off] = f2bf(v);
        }
      }
    }
  }
}

// ---------------- per-level 3-key attention ----------------
// one wave per (b, parent p); lane covers 8 dims of head (lane>>3) in each
// half (heads 0-7 via cols [0,512), heads 8-15 via cols [512,1024)).
// QKVp rows: 3072 wide (Q|K|V); KVc rows: 2048 wide (K|V).

__global__ __launch_bounds__(256) void attn_level(
    const short* __restrict__ QKVp, const short* __restrict__ KVc,
    short* __restrict__ ao, int pc, int off, int lgpc) {
  int wid = (blockIdx.x << 2) + (threadIdx.x >> 6);
  if (wid >= B_ * pc) return;
  int lane = threadIdx.x & 63;
  int b = wid >> lgpc;
  int p = wid & (pc - 1);
  int c = lane * 8;
  const short* prow = QKVp + (long)(b * NY + off + p) * 3072 + c;
  const short* c0r = KVc + ((long)(b * pc + p) * 2) * 2048 + c;
  const short* c1r = c0r + 2048;
  bf16x8 q0 = *(const bf16x8*)(prow);
  bf16x8 q1 = *(const bf16x8*)(prow + 512);
  bf16x8 kp0 = *(const bf16x8*)(prow + 1024);
  bf16x8 kp1 = *(const bf16x8*)(prow + 1536);
  bf16x8 ka0 = *(const bf16x8*)(c0r);
  bf16x8 ka1 = *(const bf16x8*)(c0r + 512);
  bf16x8 kb0 = *(const bf16x8*)(c1r);
  bf16x8 kb1 = *(const bf16x8*)(c1r + 512);
  float d0 = dot8(q0, kp0), d1 = dot8(q1, kp1);
  float d2 = dot8(q0, ka0), d3 = dot8(q1, ka1);
  float d4 = dot8(q0, kb0), d5 = dot8(q1, kb1);
#pragma unroll
  for (int s = 1; s <= 4; s <<= 1) {
    d0 += __shfl_xor(d0, s); d1 += __shfl_xor(d1, s);
    d2 += __shfl_xor(d2, s); d3 += __shfl_xor(d3, s);
    d4 += __shfl_xor(d4, s); d5 += __shfl_xor(d5, s);
  }
  d0 *= 0.125f; d1 *= 0.125f; d2 *= 0.125f;
  d3 *= 0.125f; d4 *= 0.125f; d5 *= 0.125f;
  float mA = fmaxf(d0, fmaxf(d2, d4));
  float e0 = __expf(d0 - mA), e2 = __expf(d2 - mA), e4 = __expf(d4 - mA);
  float iA = 1.f / (e0 + e2 + e4);
  e0 *= iA; e2 *= iA; e4 *= iA;
  float mB = fmaxf(d1, fmaxf(d3, d5));
  float e1 = __expf(d1 - mB), e3 = __expf(d3 - mB), e5 = __expf(d5 - mB);
  float iB = 1.f / (e1 + e3 + e5);
  e1 *= iB; e3 *= iB; e5 *= iB;
  bf16x8 vp0 = *(const bf16x8*)(prow + 2048);
  bf16x8 vp1 = *(const bf16x8*)(prow + 2560);
  bf16x8 va0 = *(const bf16x8*)(c0r + 1024);
  bf16x8 va1 = *(const bf16x8*)(c0r + 1536);
  bf16x8 vb0 = *(const bf16x8*)(c1r + 1024);
  bf16x8 vb1 = *(const bf16x8*)(c1r + 1536);
  bf16x8 s0, s1;
#pragma unroll
  for (int j = 0; j < 8; ++j) {
    s0[j] = f2bf(e0 * b2f(vp0[j]) + e2 * b2f(va0[j]) + e4 * b2f(vb0[j]));
    s1[j] = f2bf(e1 * b2f(vp1[j]) + e3 * b2f(va1[j]) + e5 * b2f(vb1[j]));
  }
  short* orow = ao + (long)(b * NY + off + p) * 1024 + c;
  *(bf16x8*)orow = s0;
  *(bf16x8*)(orow + 512) = s1;
}

// ---------------- final 13-key sparse attention ----------------
// one wave per (b, i) covering all 16 heads. K rows gathered from
// QKVx (x region, stride 3072, K at +1024) or KVy (y region, stride 2048,
// K at +0); V is always K + 1024. KVy MUST be allocated right after QKVx.

__global__ __launch_bounds__(256) void attn_final(const short* __restrict__ QKVx,
                                                  short* __restrict__ out) {
  const long XLEN = (long)B_ * N_ * 3072;
  int wid = (blockIdx.x << 2) + (threadIdx.x >> 6);
  int lane = threadIdx.x & 63;
  int b = wid >> 12;
  int i = wid & (N_ - 1);
  int c = lane * 8;
  const short* qrow = QKVx + (long)(b * N_ + i) * 3072;
  bf16x8 q0 = *(const bf16x8*)(qrow + c);
  bf16x8 q1 = *(const bf16x8*)(qrow + 512 + c);

  long offs[13];
  unsigned mbits = 0;
  offs[0] = (long)(b * N_ + i) * 3072 + 1024;
  int ncur = i;
#pragma unroll
  for (int lvl = 0; lvl < 12; ++lvl) {
    int pair, nx;
    if (lvl == 0) { pair = ncur; nx = ncur ^ 1; }
    else { pair = (ncur >> 1) + N_; nx = pair ^ 1; }
    bool valid = nx <= 2 * N_ - 3;
    int r = valid ? nx : (2 * N_ - 2);
    if (valid && pair < nx) mbits |= 1u << (lvl + 1);
    offs[lvl + 1] = (r < N_) ? ((long)(b * N_ + r) * 3072 + 1024)
                             : (XLEN + (long)(b * NY + (r - N_)) * 2048);
    ncur = nx;
  }
  float dA[13], dB[13];
#pragma unroll
  for (int k = 0; k < 13; ++k) {
    const short* kb = QKVx + offs[k];
    dA[k] = dot8(q0, *(const bf16x8*)(kb + c));
    dB[k] = dot8(q1, *(const bf16x8*)(kb + 512 + c));
  }
#pragma unroll
  for (int s = 1; s <= 4; s <<= 1) {
#pragma unroll
    for (int k = 0; k < 13; ++k) {
      dA[k] += __shfl_xor(dA[k], s);
      dB[k] += __shfl_xor(dB[k], s);
    }
  }
  float mA = -1e30f, mB = -1e30f;
#pragma unroll
  for (int k = 0; k < 13; ++k) {
    bool msk = (mbits >> k) & 1;
    dA[k] = msk ? -1e30f : dA[k] * 0.125f;
    dB[k] = msk ? -1e30f : dB[k] * 0.125f;
    mA = fmaxf(mA, dA[k]);
    mB = fmaxf(mB, dB[k]);
  }
  float sA = 0.f, sB = 0.f;
#pragma unroll
  for (int k = 0; k < 13; ++k) {
    dA[k] = __expf(dA[k] - mA); sA += dA[k];
    dB[k] = __expf(dB[k] - mB); sB += dB[k];
  }
  float iA = 1.f / sA, iB = 1.f / sB;
  float o0[8] = {0, 0, 0, 0, 0, 0, 0, 0};
  float o1[8] = {0, 0, 0, 0, 0, 0, 0, 0};
#pragma unroll
  for (int k = 0; k < 13; ++k) {
    const short* vb = QKVx + offs[k] + 1024;
    bf16x8 v0 = *(const bf16x8*)(vb + c);
    bf16x8 v1 = *(const bf16x8*)(vb + 512 + c);
    float wA = dA[k] * iA, wB = dB[k] * iB;
#pragma unroll
    for (int j = 0; j < 8; ++j) {
      o0[j] += wA * b2f(v0[j]);
      o1[j] += wB * b2f(v1[j]);
    }
  }
  bf16x8 s0, s1;
#pragma unroll
  for (int j = 0; j < 8; ++j) { s0[j] = f2bf(o0[j]); s1[j] = f2bf(o1[j]); }
  short* orow = out + (long)(b * N_ + i) * 1024 + c;
  *(bf16x8*)orow = s0;
  *(bf16x8*)(orow + 512) = s1;
}

// ---------------- host orchestration ----------------

extern "C" void kernel_launch(void* const* d_in, const int* in_sizes, int n_in,
                              void* d_out, int out_size, void* d_ws,
                              size_t ws_size, hipStream_t stream) {
  const float* x = (const float*)d_in[0];
  const float* boy = (const float*)d_in[5];
  const float* box = (const float*)d_in[10];

  char* pw = (char*)d_ws;
  auto alloc = [&](size_t n) {
    char* r = pw;
    pw += (n + 255) & ~(size_t)255;
    return r;
  };
  short* xbf  = (short*)alloc((size_t)B_ * N_ * 1024 * 2);
  short* yin  = (short*)alloc((size_t)B_ * NY * 1024 * 2);
  short* QKVp = (short*)alloc((size_t)B_ * NY * 3072 * 2);
  short* KVc  = (short*)alloc((size_t)B_ * 4096 * 2048 * 2);
  short* ao   = (short*)alloc((size_t)B_ * NY * 1024 * 2);
  short* ybf  = (short*)alloc((size_t)B_ * NY * 1024 * 2);
  // QKVx and KVy must be contiguous (attn_final indexes across both).
  // QKVx size = 2*4096*3072*2 bytes is a multiple of 256, so no pad gap.
  short* QKVx = (short*)alloc((size_t)B_ * N_ * 3072 * 2);
  short* KVy  = (short*)alloc((size_t)B_ * NY * 2048 * 2);
  short* aout = (short*)alloc((size_t)B_ * N_ * 1024 * 2);
  short* wts  = (short*)alloc((size_t)8 * 1048576 * 2);
  short* wy = wts;
  short* wx = wts + (size_t)3 * 1048576;
  short* woy = wts + (size_t)6 * 1048576;
  short* wox = wts + (size_t)7 * 1048576;
  (void)KVy;

  cvt_bf16<<<8192, 256, 0, stream>>>(x, xbf);
  SrcPtrs sp;
  sp.p[0] = (const float*)d_in[1];  // Wq_y
  sp.p[1] = (const float*)d_in[2];  // Wk_y
  sp.p[2] = (const float*)d_in[3];  // Wv_y
  sp.p[3] = (const float*)d_in[6];  // Wq_x
  sp.p[4] = (const float*)d_in[7];  // Wk_x
  sp.p[5] = (const float*)d_in[8];  // Wv_x
  sp.p[6] = (const float*)d_in[4];  // Wo_y
  sp.p[7] = (const float*)d_in[9];  // Wo_x
  cvt_weights<<<8192, 256, 0, stream>>>(sp, wts);

  pool_a<<<1920, 256, 0, stream>>>(x, yin);
  pool_b<<<128, 256, 0, stream>>>(yin);

  const long SX = (long)N_ * 1024, SY = (long)NY * 1024;

  auto gemm = [&](const short* A, const short* W, void* C, const float* bias,
                  int Mb, int Nc, long sA, long sC, int f32o) {
    dim3 g((Mb + 127) / 128, Nc / 128, B_);
    if (f32o)
      gemm_bt<1, 1><<<g, 256, 0, stream>>>(A, W, C, bias, Mb, Nc, sA, sC);
    else if (bias)
      gemm_bt<0, 1><<<g, 256, 0, stream>>>(A, W, C, bias, Mb, Nc, sA, sC);
    else
      gemm_bt<0, 0><<<g, 256, 0, stream>>>(A, W, C, nullptr, Mb, Nc, sA, sC);
  };

  // tree Q|K|V of pooled rows; level-0 children K|V from x
  gemm(yin, wy, QKVp, nullptr, NY, 3072, SY, (long)NY * 3072, 0);
  gemm(xbf, wy + 1048576, KVc, nullptr, 4096, 2048, SX, (long)4096 * 2048, 0);
  attn_level<<<(B_ * 2048) / 4, 256, 0, stream>>>(QKVp, KVc, ao, 2048, 0, 11);

  int offl = 0, pcl = 2048;
  for (int l = 1; l < 12; ++l) {
    int offprev = offl;
    offl += pcl;      // off[l]
    pcl >>= 1;        // pc[l]
    int cc = pcl * 2; // rows of previous level = children count
    gemm(ao + (long)offprev * 1024, wy + 1048576, KVc, nullptr, cc, 2048, SY,
         (long)cc * 2048, 0);
    int blocks = (B_ * pcl + 3) / 4;
    attn_level<<<blocks, 256, 0, stream>>>(QKVp, KVc, ao, pcl, offl, 11 - l);
  }

  // y = ao * Wo_y + bo_y ; final projections ; sparse attention ; output
  gemm(ao, woy, ybf, boy, NY, 1024, SY, SY, 0);
  gemm(xbf, wx, QKVx, nullptr, 4096, 3072, SX, (long)N_ * 3072, 0);
  gemm(ybf, wx + 1048576, KVy, nullptr, NY, 2048, SY, (long)NY * 2048, 0);

  attn_final<<<(B_ * N_) / 4, 256, 0, stream>>>(QKVx, aout);

  gemm(aout, wox, d_out, box, 4096, 1024, SX, SX, 1);
}